// Round 3
// baseline (417.508 us; speedup 1.0000x reference)
//
#include <hip/hip_runtime.h>
#include <hip/hip_bf16.h>

typedef unsigned short u16;
typedef unsigned int u32;

typedef __bf16 bf16x8 __attribute__((ext_vector_type(8)));
typedef float f32x4 __attribute__((ext_vector_type(4)));

// bf16 round-to-nearest-even from f32
__device__ __forceinline__ u16 f2bf(float f) {
    u32 u = __float_as_uint(f);
    return (u16)((u + 0x7fffu + ((u >> 16) & 1u)) >> 16);
}

// ---------------- Kernel A: normalize t_feat rows -> bf16 (R1, known-good)
// grid: 512 blocks (one per row c), block: 64 threads (1 wave)
__global__ void tnorm_kernel(const float* __restrict__ t_feat,
                             u16* __restrict__ tn,
                             const int* __restrict__ splitp) {
    const int row  = blockIdx.x;
    const int lane = threadIdx.x;  // 0..63, each handles 8 elems
    const float* rp = t_feat + (size_t)row * 512 + lane * 8;
    float4 x0 = *reinterpret_cast<const float4*>(rp);
    float4 x1 = *reinterpret_cast<const float4*>(rp + 4);
    float s = x0.x*x0.x + x0.y*x0.y + x0.z*x0.z + x0.w*x0.w
            + x1.x*x1.x + x1.y*x1.y + x1.z*x1.z + x1.w*x1.w;
#pragma unroll
    for (int off = 32; off > 0; off >>= 1) s += __shfl_xor(s, off, 64);
    float inv = 1.0f;
    if (*splitp == 1) inv = 1.0f / fmaxf(sqrtf(s), 1e-12f);
    u32 p0 = (u32)f2bf(x0.x*inv) | ((u32)f2bf(x0.y*inv) << 16);
    u32 p1 = (u32)f2bf(x0.z*inv) | ((u32)f2bf(x0.w*inv) << 16);
    u32 p2 = (u32)f2bf(x1.x*inv) | ((u32)f2bf(x1.y*inv) << 16);
    u32 p3 = (u32)f2bf(x1.z*inv) | ((u32)f2bf(x1.w*inv) << 16);
    uint4 packed; packed.x = p0; packed.y = p1; packed.z = p2; packed.w = p3;
    reinterpret_cast<uint4*>(tn)[row * 64 + lane] = packed;
}

// ---------------- Kernel B: per-(b,t) normalized mean over n -> bf16 (R1, known-good)
// grid: (t=256, b=32), block: 256 threads = 4 waves; wave w covers n = w+4*nn
__global__ void vmean_kernel(const float* __restrict__ v,
                             u16* __restrict__ vm,
                             const int* __restrict__ splitp) {
    const int t    = blockIdx.x;   // 0..255
    const int b    = blockIdx.y;   // 0..31
    const int tid  = threadIdx.x;  // 0..255
    const int w    = tid >> 6;     // wave 0..3
    const int lane = tid & 63;
    const int split = *splitp;
    __shared__ float lds[4 * 512];

    float acc[8];
#pragma unroll
    for (int i = 0; i < 8; i++) acc[i] = 0.f;

#pragma unroll
    for (int nn = 0; nn < 4; nn++) {
        const int n = w + nn * 4;
        const float* row = v + ((((size_t)b * 16 + n) * 256 + t) * 512) + lane * 8;
        float4 x0 = *reinterpret_cast<const float4*>(row);
        float4 x1 = *reinterpret_cast<const float4*>(row + 4);
        float s = x0.x*x0.x + x0.y*x0.y + x0.z*x0.z + x0.w*x0.w
                + x1.x*x1.x + x1.y*x1.y + x1.z*x1.z + x1.w*x1.w;
#pragma unroll
        for (int off = 32; off > 0; off >>= 1) s += __shfl_xor(s, off, 64);
        float inv = 1.0f;
        if (split == 1) inv = 1.0f / fmaxf(sqrtf(s), 1e-12f);
        acc[0] += x0.x * inv; acc[1] += x0.y * inv;
        acc[2] += x0.z * inv; acc[3] += x0.w * inv;
        acc[4] += x1.x * inv; acc[5] += x1.y * inv;
        acc[6] += x1.z * inv; acc[7] += x1.w * inv;
    }
    // cross-wave combine via LDS
#pragma unroll
    for (int i = 0; i < 8; i += 2) {
        float2 p; p.x = acc[i]; p.y = acc[i + 1];
        *reinterpret_cast<float2*>(&lds[w * 512 + lane * 8 + i]) = p;
    }
    __syncthreads();
    float2 r; r.x = 0.f; r.y = 0.f;
#pragma unroll
    for (int w2 = 0; w2 < 4; w2++) {
        float2 p = *reinterpret_cast<const float2*>(&lds[w2 * 512 + tid * 2]);
        r.x += p.x; r.y += p.y;
    }
    r.x *= (1.0f / 16.0f); r.y *= (1.0f / 16.0f);
    u32 packed = (u32)f2bf(r.x) | ((u32)f2bf(r.y) << 16);
    reinterpret_cast<u32*>(vm)[(((size_t)b * 256 + t) << 8) + tid] = packed;
}

// ---------------- Kernel C (new): barrier-free GEMM, B in registers --------
// out[b][c][t] = <tn[c,:], vm[b,t,:]> / tau
// grid: (tTiles=16, b=32) = 512 blocks; block = 256 thr = 4 waves.
// Each wave: B frag (16t x 512k) = 64 VGPRs loaded once from vm (global),
// then streams A fragments of tn from L2 (per wave-inst: 16 rows x 64B line),
// 2 independent MFMA chains for ILP. No LDS, no barriers.
__global__ __launch_bounds__(256) void gemm_kernel(const u16* __restrict__ tn,
                                                   const u16* __restrict__ vm,
                                                   float* __restrict__ out) {
    const int tt   = blockIdx.x;   // t tile, 16 wide
    const int b    = blockIdx.y;
    const int tid  = threadIdx.x;
    const int w    = tid >> 6;     // wave 0..3 -> owns c in [w*128, w*128+128)
    const int lane = tid & 63;
    const int quad = lane >> 4;
    const int l15  = lane & 15;
    const int t0   = tt * 16;

    // B fragments: breg[kk] holds vm[b, t0+l15, kk*32+quad*8 .. +7]
    const uint4* gB = reinterpret_cast<const uint4*>(vm) + (size_t)b * 256 * 64;
    bf16x8 breg[16];
#pragma unroll
    for (int kk = 0; kk < 16; ++kk) {
        uint4 bv = gB[(t0 + l15) * 64 + kk * 4 + quad];
        breg[kk] = *reinterpret_cast<const bf16x8*>(&bv);
    }

    const uint4* gA = reinterpret_cast<const uint4*>(tn);
    const float sc = 1.0f / 0.07f;
    float* ob = out + (size_t)b * (512 * 256);

#pragma unroll 1
    for (int f = 0; f < 8; f += 2) {
        const int cb0 = w * 128 + f * 16;
        const int cb1 = cb0 + 16;
        f32x4 a0 = {};
        f32x4 a1 = {};
#pragma unroll 4
        for (int kk = 0; kk < 16; ++kk) {
            uint4 av0 = gA[(cb0 + l15) * 64 + kk * 4 + quad];
            uint4 av1 = gA[(cb1 + l15) * 64 + kk * 4 + quad];
            a0 = __builtin_amdgcn_mfma_f32_16x16x32_bf16(
                *reinterpret_cast<const bf16x8*>(&av0), breg[kk], a0, 0, 0, 0);
            a1 = __builtin_amdgcn_mfma_f32_16x16x32_bf16(
                *reinterpret_cast<const bf16x8*>(&av1), breg[kk], a1, 0, 0, 0);
        }
#pragma unroll
        for (int r = 0; r < 4; ++r) {
            ob[(cb0 + quad * 4 + r) * 256 + t0 + l15] = a0[r] * sc;
            ob[(cb1 + quad * 4 + r) * 256 + t0 + l15] = a1[r] * sc;
        }
    }
}

extern "C" void kernel_launch(void* const* d_in, const int* in_sizes, int n_in,
                              void* d_out, int out_size, void* d_ws, size_t ws_size,
                              hipStream_t stream) {
    const float* v_feat = (const float*)d_in[0];   // (32,16,256,512)
    const float* t_feat = (const float*)d_in[1];   // (512,512)
    const int*   splitp = (const int*)d_in[2];
    float* out = (float*)d_out;                    // (32,512,256)

    u16* tn = (u16*)d_ws;                 // 512*512 bf16    = 512 KB
    u16* vm = tn + 512 * 512;             // 32*256*512 bf16 = 8 MB

    tnorm_kernel<<<dim3(512), dim3(64), 0, stream>>>(t_feat, tn, splitp);
    vmean_kernel<<<dim3(256, 32), dim3(256), 0, stream>>>(v_feat, vm, splitp);
    gemm_kernel<<<dim3(16, 32), dim3(256), 0, stream>>>(tn, vm, out);
}

// Round 4
// 366.789 us; speedup vs baseline: 1.1383x; 1.1383x over previous
//
#include <hip/hip_runtime.h>
#include <hip/hip_bf16.h>

typedef unsigned short u16;
typedef unsigned int u32;

typedef __bf16 bf16x8 __attribute__((ext_vector_type(8)));
typedef float f32x4 __attribute__((ext_vector_type(4)));

// bf16 round-to-nearest-even from f32
__device__ __forceinline__ u16 f2bf(float f) {
    u32 u = __float_as_uint(f);
    return (u16)((u + 0x7fffu + ((u >> 16) & 1u)) >> 16);
}

// ---- Kernel B: per-(b,t) normalized mean over n -> bf16, with tnorm fused
// grid: (t=256, b=33). by<32: vmean for (b=by, t=bx). by==32: tnorm slice —
// waves 0,1 of blocks bx normalize t_feat rows 2*bx, 2*bx+1 (512 rows total).
__global__ void vmean_kernel(const float* __restrict__ v,
                             const float* __restrict__ t_feat,
                             u16* __restrict__ vm,
                             u16* __restrict__ tn,
                             const int* __restrict__ splitp) {
    const int bx   = blockIdx.x;   // 0..255
    const int by   = blockIdx.y;   // 0..32
    const int tid  = threadIdx.x;  // 0..255
    const int w    = tid >> 6;     // wave 0..3
    const int lane = tid & 63;
    const int split = *splitp;

    if (by == 32) {
        // ---- tnorm slice: one wave per row, rows 2*bx + w (w<2) ----
        if (w >= 2) return;
        const int row = bx * 2 + w;
        const float* rp = t_feat + (size_t)row * 512 + lane * 8;
        float4 x0 = *reinterpret_cast<const float4*>(rp);
        float4 x1 = *reinterpret_cast<const float4*>(rp + 4);
        float s = x0.x*x0.x + x0.y*x0.y + x0.z*x0.z + x0.w*x0.w
                + x1.x*x1.x + x1.y*x1.y + x1.z*x1.z + x1.w*x1.w;
#pragma unroll
        for (int off = 32; off > 0; off >>= 1) s += __shfl_xor(s, off, 64);
        float inv = 1.0f;
        if (split == 1) inv = 1.0f / fmaxf(sqrtf(s), 1e-12f);
        u32 p0 = (u32)f2bf(x0.x*inv) | ((u32)f2bf(x0.y*inv) << 16);
        u32 p1 = (u32)f2bf(x0.z*inv) | ((u32)f2bf(x0.w*inv) << 16);
        u32 p2 = (u32)f2bf(x1.x*inv) | ((u32)f2bf(x1.y*inv) << 16);
        u32 p3 = (u32)f2bf(x1.z*inv) | ((u32)f2bf(x1.w*inv) << 16);
        uint4 pk; pk.x = p0; pk.y = p1; pk.z = p2; pk.w = p3;
        reinterpret_cast<uint4*>(tn)[row * 64 + lane] = pk;
        return;
    }

    const int t = bx;
    const int b = by;
    __shared__ float lds[4 * 512];

    float acc[8];
#pragma unroll
    for (int i = 0; i < 8; i++) acc[i] = 0.f;

#pragma unroll
    for (int nn = 0; nn < 4; nn++) {
        const int n = w + nn * 4;
        const float* row = v + ((((size_t)b * 16 + n) * 256 + t) * 512) + lane * 8;
        float4 x0 = *reinterpret_cast<const float4*>(row);
        float4 x1 = *reinterpret_cast<const float4*>(row + 4);
        float s = x0.x*x0.x + x0.y*x0.y + x0.z*x0.z + x0.w*x0.w
                + x1.x*x1.x + x1.y*x1.y + x1.z*x1.z + x1.w*x1.w;
#pragma unroll
        for (int off = 32; off > 0; off >>= 1) s += __shfl_xor(s, off, 64);
        float inv = 1.0f;
        if (split == 1) inv = 1.0f / fmaxf(sqrtf(s), 1e-12f);
        acc[0] += x0.x * inv; acc[1] += x0.y * inv;
        acc[2] += x0.z * inv; acc[3] += x0.w * inv;
        acc[4] += x1.x * inv; acc[5] += x1.y * inv;
        acc[6] += x1.z * inv; acc[7] += x1.w * inv;
    }
    // cross-wave combine via LDS
#pragma unroll
    for (int i = 0; i < 8; i += 2) {
        float2 p; p.x = acc[i]; p.y = acc[i + 1];
        *reinterpret_cast<float2*>(&lds[w * 512 + lane * 8 + i]) = p;
    }
    __syncthreads();
    float2 r; r.x = 0.f; r.y = 0.f;
#pragma unroll
    for (int w2 = 0; w2 < 4; w2++) {
        float2 p = *reinterpret_cast<const float2*>(&lds[w2 * 512 + tid * 2]);
        r.x += p.x; r.y += p.y;
    }
    r.x *= (1.0f / 16.0f); r.y *= (1.0f / 16.0f);
    u32 packed = (u32)f2bf(r.x) | ((u32)f2bf(r.y) << 16);
    reinterpret_cast<u32*>(vm)[(((size_t)b * 256 + t) << 8) + tid] = packed;
}

// ---- Kernel C: out[b][c][t] = <tn[c,:], vm[b,t,:]> / tau  (R1 structure,
// tile widened to 128c x 64t: 8 MFMA per 6 ds_read_b128, half the barriers
// per output vs R1's 64x64)
// grid: (cTiles=4, tTiles=4, b=32) = 512 blocks, block 256 = 4 waves.
// wave (wm=w&1, wn=w>>1) computes 64c x 32t via 4x2 frags of 16x16x32.
__global__ __launch_bounds__(256) void gemm_kernel(const u16* __restrict__ tn,
                                                   const u16* __restrict__ vm,
                                                   float* __restrict__ out) {
    const int bx   = blockIdx.x;   // c tile (128 wide)
    const int by   = blockIdx.y;   // t tile (64 wide)
    const int b    = blockIdx.z;
    const int tid  = threadIdx.x;
    const int lane = tid & 63;
    const int wid  = tid >> 6;
    const int wm   = wid & 1;      // c dir (64 each)
    const int wn   = wid >> 1;     // t dir (32 each)
    const int quad = lane >> 4;
    const int l15  = lane & 15;

    // +8 bf16 pad per row -> 144B stride: <=2-way LDS conflicts (free)
    __shared__ u16 At[128 * 72];
    __shared__ u16 Bt[64 * 72];

    const int c0 = bx * 128, t0 = by * 64;
    f32x4 acc[4][2] = {};

    const int lrow = tid >> 3;        // 0..31 (staging row base)
    const int lcol = (tid & 7) * 8;   // staging col in elements

    const uint4* gA = reinterpret_cast<const uint4*>(tn);
    const uint4* gB = reinterpret_cast<const uint4*>(vm) + (size_t)b * 256 * 64;

    for (int k0 = 0; k0 < 512; k0 += 64) {
#pragma unroll
        for (int it = 0; it < 4; it++) {
            int row = lrow + it * 32;
            uint4 av = gA[(c0 + row) * 64 + (k0 >> 3) + (tid & 7)];
            *reinterpret_cast<uint4*>(&At[row * 72 + lcol]) = av;
        }
#pragma unroll
        for (int it = 0; it < 2; it++) {
            int row = lrow + it * 32;
            uint4 bv = gB[(t0 + row) * 64 + (k0 >> 3) + (tid & 7)];
            *reinterpret_cast<uint4*>(&Bt[row * 72 + lcol]) = bv;
        }
        __syncthreads();
#pragma unroll
        for (int kk = 0; kk < 64; kk += 32) {
            bf16x8 af[4], bfr[2];
#pragma unroll
            for (int i = 0; i < 4; i++)
                af[i] = *reinterpret_cast<const bf16x8*>(
                    &At[(wm * 64 + i * 16 + l15) * 72 + kk + quad * 8]);
#pragma unroll
            for (int j = 0; j < 2; j++)
                bfr[j] = *reinterpret_cast<const bf16x8*>(
                    &Bt[(wn * 32 + j * 16 + l15) * 72 + kk + quad * 8]);
#pragma unroll
            for (int i = 0; i < 4; i++)
#pragma unroll
                for (int j = 0; j < 2; j++)
                    acc[i][j] = __builtin_amdgcn_mfma_f32_16x16x32_bf16(
                        af[i], bfr[j], acc[i][j], 0, 0, 0);
        }
        __syncthreads();
    }

    const float s = 1.0f / 0.07f;
    float* ob = out + (size_t)b * 131072;  // 512*256
#pragma unroll
    for (int i = 0; i < 4; i++)
#pragma unroll
        for (int j = 0; j < 2; j++)
#pragma unroll
            for (int r = 0; r < 4; r++) {
                int c = c0 + wm * 64 + i * 16 + quad * 4 + r;
                int t = t0 + wn * 32 + j * 16 + l15;
                ob[c * 256 + t] = acc[i][j][r] * s;
            }
}

extern "C" void kernel_launch(void* const* d_in, const int* in_sizes, int n_in,
                              void* d_out, int out_size, void* d_ws, size_t ws_size,
                              hipStream_t stream) {
    const float* v_feat = (const float*)d_in[0];   // (32,16,256,512)
    const float* t_feat = (const float*)d_in[1];   // (512,512)
    const int*   splitp = (const int*)d_in[2];
    float* out = (float*)d_out;                    // (32,512,256)

    u16* tn = (u16*)d_ws;                 // 512*512 bf16    = 512 KB
    u16* vm = tn + 512 * 512;             // 32*256*512 bf16 = 8 MB

    vmean_kernel<<<dim3(256, 33), dim3(256), 0, stream>>>(v_feat, t_feat, vm, tn, splitp);
    gemm_kernel<<<dim3(4, 4, 32), dim3(256), 0, stream>>>(tn, vm, out);
}